// Round 2
// baseline (714.576 us; speedup 1.0000x reference)
//
#include <hip/hip_runtime.h>

#define N_NODES 100000
#define N_EDGES 1250000

typedef __bf16 bf16x8 __attribute__((ext_vector_type(8)));
typedef __bf16 bf16x4 __attribute__((ext_vector_type(4)));
typedef _Float16 f16x8 __attribute__((ext_vector_type(8)));
typedef float  f32x4  __attribute__((ext_vector_type(4)));

#define MFMA16(a, b, c) __builtin_amdgcn_mfma_f32_16x16x32_bf16((a), (b), (c), 0, 0, 0)

// bit-pun helpers (all LDS goes through one __bf16-typed buffer; f16 values
// are stored/loaded as raw 16-bit patterns to avoid aliasing hazards)
__device__ __forceinline__ unsigned short bf2u(__bf16 x) {
    union { __bf16 b; unsigned short u; } c; c.b = x; return c.u;
}
__device__ __forceinline__ _Float16 u2h(unsigned short x) {
    union { _Float16 h; unsigned short u; } c; c.u = x; return c.h;
}

// LDS address swizzle: 16B chunks xor'd by row&7 so A-frag b128 reads and
// row-major staging writes both hit the structural LDS minimum (no conflicts).
__device__ __forceinline__ int swz(int row, int k) {
    return row * 64 + (((k >> 3) ^ (row & 7)) << 3) + (k & 7);
}

// Stage 32 rows (this wave's slice) of a row-major [nrows x 64] fp32 matrix
// into LDS as bf16, swizzled. Coalesced float4 loads; barrier-free (each wave
// touches only rows [wb, wb+32)).
__device__ __forceinline__ void stage_rows_bf16(
    const float* __restrict__ srcmat, long row0, int wb, int lane,
    __bf16* sT, long nrows)
{
#pragma unroll
    for (int i = 0; i < 8; ++i) {
        const int f = (i * 64 + lane) * 4;   // flat over 32*64 floats
        const int rl = f >> 6;
        const int k  = f & 63;
        const int r_loc = wb + rl;
        const long r = row0 + r_loc;
        float4 v = {0.f, 0.f, 0.f, 0.f};
        if (r < nrows) v = *(const float4*)&srcmat[(size_t)r * 64 + k];
        bf16x4 pk = { (__bf16)v.x, (__bf16)v.y, (__bf16)v.z, (__bf16)v.w };
        *(bf16x4*)&sT[swz(r_loc, k)] = pk;
    }
}

// A-frag for mfma_f32_16x16x32_bf16: lane holds A[m=lane&15][k=quad*8+j]
__device__ __forceinline__ bf16x8 afrag(const __bf16* sT, int row, int ks, int q) {
    return *(const bf16x8*)&sT[swz(row, ks * 32 + q * 8)];
}

// ---------------------------------------------------------------------------
// prep: convert the 5 weight matrices to bf16 in B-frag order in ws.
// Frag slot s = (ks*NT + nt)*64 + lane holds B[k=ks*32+(lane>>4)*8+j][n=nt*16+(lane&15)]
// ---------------------------------------------------------------------------
__device__ __forceinline__ void conv_frag(const float* __restrict__ W, int N,
                                          __bf16* __restrict__ dst, int tid) {
    const int NT = N / 16;
    const int slots = 2 * NT * 64;
    for (int s = tid; s < slots; s += 256) {
        const int ks = s / (NT * 64);
        const int nt = (s / 64) % NT;
        const int lane = s % 64;
        const int q = lane >> 4, lc = lane & 15;
#pragma unroll
        for (int j = 0; j < 8; ++j) {
            const int k = ks * 32 + q * 8 + j;
            dst[(size_t)s * 8 + j] = (__bf16)W[(size_t)k * N + nt * 16 + lc];
        }
    }
}

__global__ __launch_bounds__(256) void prep_kernel(
    const float* __restrict__ Wv, const float* __restrict__ Wr,
    const float* __restrict__ We, const float* __restrict__ W1,
    const float* __restrict__ W2,
    __bf16* wfv, __bf16* wfr, __bf16* wfe, __bf16* wf1, __bf16* wf2)
{
    const int t = threadIdx.x;
    conv_frag(Wv, 64, wfv, t);
    conv_frag(Wr, 64, wfr, t);
    conv_frag(We, 64, wfe, t);
    conv_frag(W1, 64, wf1, t);
    conv_frag(W2, 32, wf2, t);
}

// ---------------------------------------------------------------------------
// node: vskb = bf16(feat@Wv + bv), vrkb = bf16(feat@Wr + br). 128 nodes/block.
// ---------------------------------------------------------------------------
__global__ __launch_bounds__(256, 4) void node_kernel(
    const float* __restrict__ feat,
    const float* __restrict__ bv, const float* __restrict__ br,
    const __bf16* __restrict__ wfv, const __bf16* __restrict__ wfr,
    __bf16* __restrict__ vskb, __bf16* __restrict__ vrkb)
{
    __shared__ __align__(16) __bf16 sT[128 * 64];
    const int tid = threadIdx.x;
    const int lane = tid & 63, w = tid >> 6;
    const int q = lane >> 4, lc = lane & 15;
    const long n0 = (long)blockIdx.x * 128;
    const int wb = w * 32;

    stage_rows_bf16(feat, n0, wb, lane, sT, (long)N_NODES);

    bf16x8 a[2][2];
#pragma unroll
    for (int mt = 0; mt < 2; ++mt)
#pragma unroll
        for (int ks = 0; ks < 2; ++ks)
            a[mt][ks] = afrag(sT, wb + mt * 16 + lc, ks, q);

    const __bf16* wf[2] = {wfv, wfr};
    const float* bias[2] = {bv, br};
    __bf16* dstp[2] = {vskb, vrkb};

    for (int m = 0; m < 2; ++m) {
        bf16x8 bfr[4][2];
#pragma unroll
        for (int nt = 0; nt < 4; ++nt)
#pragma unroll
            for (int ks = 0; ks < 2; ++ks)
                bfr[nt][ks] = *(const bf16x8*)&wf[m][((size_t)(ks * 4 + nt) * 64 + lane) * 8];

        f32x4 acc[2][4];
#pragma unroll
        for (int mt = 0; mt < 2; ++mt)
#pragma unroll
            for (int nt = 0; nt < 4; ++nt) {
                f32x4 z = {0.f, 0.f, 0.f, 0.f};
                acc[mt][nt] = z;
            }
#pragma unroll
        for (int ks = 0; ks < 2; ++ks)
#pragma unroll
            for (int mt = 0; mt < 2; ++mt)
#pragma unroll
                for (int nt = 0; nt < 4; ++nt)
                    acc[mt][nt] = MFMA16(a[mt][ks], bfr[nt][ks], acc[mt][nt]);

        float bb[4];
#pragma unroll
        for (int nt = 0; nt < 4; ++nt) bb[nt] = bias[m][nt * 16 + lc];

#pragma unroll
        for (int mt = 0; mt < 2; ++mt)
#pragma unroll
            for (int r = 0; r < 4; ++r) {
                const long node = n0 + wb + mt * 16 + q * 4 + r;
                if (node < N_NODES) {
#pragma unroll
                    for (int nt = 0; nt < 4; ++nt)
                        dstp[m][(size_t)node * 64 + nt * 16 + lc] =
                            (__bf16)(acc[mt][nt][r] + bb[nt]);
                }
            }
    }
}

// ---------------------------------------------------------------------------
// edge: h = relu(ek + vsk[src] + vrk[dst] + bek); h1 = relu(h@W1+b1);
//       out = relu(h1@W2+b2). 128 edges/block, barrier-free (wave-private rows).
// Single 16KB LDS buffer, reused 4 ways: efeat(bf16) -> gsum(f16) -> h(bf16)
//   -> h1(bf16).
// Gathers: lane l pulls 16B chunk (l&7) of edge (l>>3)'s vsk AND vrk rows,
//   pre-sums them in f32, stores the sum as f16 (10-bit mantissa, error
//   <=0.004 vs f32 path) into the efeat buffer right after A-frags are pulled.
// Epilogue then needs ONE ds_read_u16 + one add per element instead of two.
// 16KB LDS + VGPR<=64 -> 8 blocks/CU -> 2x resident waves vs the 32KB version.
// ---------------------------------------------------------------------------
__global__ __launch_bounds__(256, 8) void edge_kernel(
    const float* __restrict__ efeat,
    const int* __restrict__ src, const int* __restrict__ dst,
    const __bf16* __restrict__ vskb, const __bf16* __restrict__ vrkb,
    const __bf16* __restrict__ wfe, const __bf16* __restrict__ wf1,
    const __bf16* __restrict__ wf2,
    const float* __restrict__ bek, const float* __restrict__ b1,
    const float* __restrict__ b2,
    float* __restrict__ out)
{
    __shared__ __align__(16) __bf16 sT[128 * 64];
    const int tid = threadIdx.x;
    const int lane = tid & 63, w = tid >> 6;
    const int q = lane >> 4, lc = lane & 15;
    const long e0 = (long)blockIdx.x * 128;
    const int wb = w * 32;
    const int jlo = lane >> 3;   // edge-within-group-of-8
    const int ch  = lane & 7;    // 16B (8-elem) chunk within the 64-col row

    // ---- wave-cooperative gathers, issued FIRST so L2/L3 latency hides
    //      under efeat staging + A-frag pulls; pre-summed to f16 in regs ----
    f16x8 gsum[4];
#pragma unroll
    for (int i = 0; i < 4; ++i) {
        const int r_loc = wb + i * 8 + jlo;
        const long e = e0 + r_loc;
        int si = 0, di = 0;
        if (e < (long)N_EDGES) { si = src[e]; di = dst[e]; }
        bf16x8 gs = *(const bf16x8*)&vskb[(size_t)si * 64 + ch * 8];
        bf16x8 gd = *(const bf16x8*)&vrkb[(size_t)di * 64 + ch * 8];
        f16x8 s;
#pragma unroll
        for (int j = 0; j < 8; ++j)
            s[j] = (_Float16)((float)gs[j] + (float)gd[j]);
        gsum[i] = s;
    }

    // ---- stage efeat (own 32 rows) + pull A-frags ----
    stage_rows_bf16(efeat, e0, wb, lane, sT, (long)N_EDGES);

    bf16x8 a[2][2];
#pragma unroll
    for (int mt = 0; mt < 2; ++mt)
#pragma unroll
        for (int ks = 0; ks < 2; ++ks)
            a[mt][ks] = afrag(sT, wb + mt * 16 + lc, ks, q);

    // ---- efeat now dead for this wave's rows: park f16 gsum in sT (bit-cast,
    //      same 2B slots, same swizzle) ----
#pragma unroll
    for (int i = 0; i < 4; ++i)
        *(bf16x8*)&sT[swz(wb + i * 8 + jlo, ch * 8)] =
            __builtin_bit_cast(bf16x8, gsum[i]);

    // ---- GEMM1: ek = efeat @ Wek ----
    {
        bf16x8 bfr[4][2];
#pragma unroll
        for (int nt = 0; nt < 4; ++nt)
#pragma unroll
            for (int ks = 0; ks < 2; ++ks)
                bfr[nt][ks] = *(const bf16x8*)&wfe[((size_t)(ks * 4 + nt) * 64 + lane) * 8];

        f32x4 acc[2][4];
#pragma unroll
        for (int mt = 0; mt < 2; ++mt)
#pragma unroll
            for (int nt = 0; nt < 4; ++nt) {
                f32x4 z = {0.f, 0.f, 0.f, 0.f};
                acc[mt][nt] = z;
            }
#pragma unroll
        for (int ks = 0; ks < 2; ++ks)
#pragma unroll
            for (int mt = 0; mt < 2; ++mt)
#pragma unroll
                for (int nt = 0; nt < 4; ++nt)
                    acc[mt][nt] = MFMA16(a[mt][ks], bfr[nt][ks], acc[mt][nt]);

        float bb[4];
#pragma unroll
        for (int nt = 0; nt < 4; ++nt) bb[nt] = bek[nt * 16 + lc];

        // ---- epilogue 1: read f16 gsum, h = relu(acc + gsum + b), write h
        //      (bf16) in place. Each 2B slot: one reader=writer lane, ordered.
#pragma unroll
        for (int mt = 0; mt < 2; ++mt)
#pragma unroll
            for (int r = 0; r < 4; ++r) {
                const int e_loc = wb + mt * 16 + q * 4 + r;
#pragma unroll
                for (int nt = 0; nt < 4; ++nt) {
                    const int col = nt * 16 + lc;
                    const int idx = swz(e_loc, col);
                    const float g = (float)u2h(bf2u(sT[idx]));
                    const float hv = fmaxf(acc[mt][nt][r] + g + bb[nt], 0.f);
                    sT[idx] = (__bf16)hv;
                }
            }
    }

    // ---- GEMM2: h1 = relu(h @ W1 + b1) ----
    {
        bf16x8 a2[2][2];
#pragma unroll
        for (int mt = 0; mt < 2; ++mt)
#pragma unroll
            for (int ks = 0; ks < 2; ++ks)
                a2[mt][ks] = afrag(sT, wb + mt * 16 + lc, ks, q);

        bf16x8 bfr[4][2];
#pragma unroll
        for (int nt = 0; nt < 4; ++nt)
#pragma unroll
            for (int ks = 0; ks < 2; ++ks)
                bfr[nt][ks] = *(const bf16x8*)&wf1[((size_t)(ks * 4 + nt) * 64 + lane) * 8];

        f32x4 acc[2][4];
#pragma unroll
        for (int mt = 0; mt < 2; ++mt)
#pragma unroll
            for (int nt = 0; nt < 4; ++nt) {
                f32x4 z = {0.f, 0.f, 0.f, 0.f};
                acc[mt][nt] = z;
            }
#pragma unroll
        for (int ks = 0; ks < 2; ++ks)
#pragma unroll
            for (int mt = 0; mt < 2; ++mt)
#pragma unroll
                for (int nt = 0; nt < 4; ++nt)
                    acc[mt][nt] = MFMA16(a2[mt][ks], bfr[nt][ks], acc[mt][nt]);

        float bb[4];
#pragma unroll
        for (int nt = 0; nt < 4; ++nt) bb[nt] = b1[nt * 16 + lc];

#pragma unroll
        for (int mt = 0; mt < 2; ++mt)
#pragma unroll
            for (int r = 0; r < 4; ++r) {
                const int e_loc = wb + mt * 16 + q * 4 + r;
#pragma unroll
                for (int nt = 0; nt < 4; ++nt) {
                    const int col = nt * 16 + lc;
                    const float hv = fmaxf(acc[mt][nt][r] + bb[nt], 0.f);
                    sT[swz(e_loc, col)] = (__bf16)hv;
                }
            }
    }

    // ---- GEMM3: out = relu(h1 @ W2 + b2) ----
    {
        bf16x8 a3[2][2];
#pragma unroll
        for (int mt = 0; mt < 2; ++mt)
#pragma unroll
            for (int ks = 0; ks < 2; ++ks)
                a3[mt][ks] = afrag(sT, wb + mt * 16 + lc, ks, q);

        bf16x8 bfr[2][2];
#pragma unroll
        for (int nt = 0; nt < 2; ++nt)
#pragma unroll
            for (int ks = 0; ks < 2; ++ks)
                bfr[nt][ks] = *(const bf16x8*)&wf2[((size_t)(ks * 2 + nt) * 64 + lane) * 8];

        f32x4 acc[2][2];
#pragma unroll
        for (int mt = 0; mt < 2; ++mt)
#pragma unroll
            for (int nt = 0; nt < 2; ++nt) {
                f32x4 z = {0.f, 0.f, 0.f, 0.f};
                acc[mt][nt] = z;
            }
#pragma unroll
        for (int ks = 0; ks < 2; ++ks)
#pragma unroll
            for (int mt = 0; mt < 2; ++mt)
#pragma unroll
                for (int nt = 0; nt < 2; ++nt)
                    acc[mt][nt] = MFMA16(a3[mt][ks], bfr[nt][ks], acc[mt][nt]);

        float bb[2] = {b2[lc], b2[16 + lc]};

#pragma unroll
        for (int mt = 0; mt < 2; ++mt)
#pragma unroll
            for (int r = 0; r < 4; ++r) {
                const long e = e0 + wb + mt * 16 + q * 4 + r;
                if (e < N_EDGES) {
#pragma unroll
                    for (int nt = 0; nt < 2; ++nt)
                        out[(size_t)e * 32 + nt * 16 + lc] =
                            fmaxf(acc[mt][nt][r] + bb[nt], 0.f);
                }
            }
    }
}

extern "C" void kernel_launch(void* const* d_in, const int* in_sizes, int n_in,
                              void* d_out, int out_size, void* d_ws, size_t ws_size,
                              hipStream_t stream) {
    const float* feat  = (const float*)d_in[0];
    const float* efeat = (const float*)d_in[1];
    const int*   src   = (const int*)d_in[2];
    const int*   dst   = (const int*)d_in[3];
    const float* W_vsk = (const float*)d_in[4];
    const float* b_vsk = (const float*)d_in[5];
    const float* W_vrk = (const float*)d_in[6];
    const float* b_vrk = (const float*)d_in[7];
    const float* W_ek  = (const float*)d_in[8];
    const float* b_ek  = (const float*)d_in[9];
    const float* W1    = (const float*)d_in[10];
    const float* b1    = (const float*)d_in[11];
    const float* W2    = (const float*)d_in[12];
    const float* b2    = (const float*)d_in[13];
    float* out = (float*)d_out;

    // ws: vskb(12.8MB) | vrkb(12.8MB) | 5 weight frag blocks (36KB)
    __bf16* vskb = (__bf16*)d_ws;
    __bf16* vrkb = vskb + (size_t)N_NODES * 64;
    __bf16* wfv  = vrkb + (size_t)N_NODES * 64;
    __bf16* wfr  = wfv + 4096;
    __bf16* wfe  = wfr + 4096;
    __bf16* wf1  = wfe + 4096;
    __bf16* wf2  = wf1 + 4096;   // 2048 elems

    prep_kernel<<<1, 256, 0, stream>>>(W_vsk, W_vrk, W_ek, W1, W2,
                                       wfv, wfr, wfe, wf1, wf2);

    const int node_blocks = (N_NODES + 127) / 128;   // 782
    node_kernel<<<node_blocks, 256, 0, stream>>>(feat, b_vsk, b_vrk,
                                                 wfv, wfr, vskb, vrkb);

    const int edge_blocks = (N_EDGES + 127) / 128;   // 9766
    edge_kernel<<<edge_blocks, 256, 0, stream>>>(efeat, src, dst, vskb, vrkb,
                                                 wfe, wf1, wf2,
                                                 b_ek, b1, b2, out);
}

// Round 3
// 631.350 us; speedup vs baseline: 1.1318x; 1.1318x over previous
//
#include <hip/hip_runtime.h>

#define N_NODES 100000
#define N_EDGES 1250000

typedef __bf16 bf16x8 __attribute__((ext_vector_type(8)));
typedef __bf16 bf16x4 __attribute__((ext_vector_type(4)));
typedef _Float16 f16x8 __attribute__((ext_vector_type(8)));
typedef float  f32x4  __attribute__((ext_vector_type(4)));

#define MFMA16(a, b, c) __builtin_amdgcn_mfma_f32_16x16x32_bf16((a), (b), (c), 0, 0, 0)

// bit-pun helpers (all LDS goes through one __bf16-typed buffer; f16 values
// are stored/loaded as raw 16-bit patterns to avoid aliasing hazards)
__device__ __forceinline__ unsigned short bf2u(__bf16 x) {
    union { __bf16 b; unsigned short u; } c; c.b = x; return c.u;
}
__device__ __forceinline__ _Float16 u2h(unsigned short x) {
    union { _Float16 h; unsigned short u; } c; c.u = x; return c.h;
}

// LDS address swizzle: 16B chunks xor'd by row&7 so A-frag b128 reads and
// row-major staging writes both hit the structural LDS minimum (no conflicts).
__device__ __forceinline__ int swz(int row, int k) {
    return row * 64 + (((k >> 3) ^ (row & 7)) << 3) + (k & 7);
}

// Stage 32 rows (this wave's slice) of a row-major [nrows x 64] fp32 matrix
// into LDS as bf16, swizzled. Coalesced float4 loads; barrier-free (each wave
// touches only rows [wb, wb+32)).
__device__ __forceinline__ void stage_rows_bf16(
    const float* __restrict__ srcmat, long row0, int wb, int lane,
    __bf16* sT, long nrows)
{
#pragma unroll
    for (int i = 0; i < 8; ++i) {
        const int f = (i * 64 + lane) * 4;   // flat over 32*64 floats
        const int rl = f >> 6;
        const int k  = f & 63;
        const int r_loc = wb + rl;
        const long r = row0 + r_loc;
        float4 v = {0.f, 0.f, 0.f, 0.f};
        if (r < nrows) v = *(const float4*)&srcmat[(size_t)r * 64 + k];
        bf16x4 pk = { (__bf16)v.x, (__bf16)v.y, (__bf16)v.z, (__bf16)v.w };
        *(bf16x4*)&sT[swz(r_loc, k)] = pk;
    }
}

// A-frag for mfma_f32_16x16x32_bf16: lane holds A[m=lane&15][k=quad*8+j]
__device__ __forceinline__ bf16x8 afrag(const __bf16* sT, int row, int ks, int q) {
    return *(const bf16x8*)&sT[swz(row, ks * 32 + q * 8)];
}

// ---------------------------------------------------------------------------
// prep: convert the 5 weight matrices to bf16 in B-frag order in ws.
// Frag slot s = (ks*NT + nt)*64 + lane holds B[k=ks*32+(lane>>4)*8+j][n=nt*16+(lane&15)]
// ---------------------------------------------------------------------------
__device__ __forceinline__ void conv_frag(const float* __restrict__ W, int N,
                                          __bf16* __restrict__ dst, int tid) {
    const int NT = N / 16;
    const int slots = 2 * NT * 64;
    for (int s = tid; s < slots; s += 256) {
        const int ks = s / (NT * 64);
        const int nt = (s / 64) % NT;
        const int lane = s % 64;
        const int q = lane >> 4, lc = lane & 15;
#pragma unroll
        for (int j = 0; j < 8; ++j) {
            const int k = ks * 32 + q * 8 + j;
            dst[(size_t)s * 8 + j] = (__bf16)W[(size_t)k * N + nt * 16 + lc];
        }
    }
}

__global__ __launch_bounds__(256) void prep_kernel(
    const float* __restrict__ Wv, const float* __restrict__ Wr,
    const float* __restrict__ We, const float* __restrict__ W1,
    const float* __restrict__ W2,
    __bf16* wfv, __bf16* wfr, __bf16* wfe, __bf16* wf1, __bf16* wf2)
{
    const int t = threadIdx.x;
    conv_frag(Wv, 64, wfv, t);
    conv_frag(Wr, 64, wfr, t);
    conv_frag(We, 64, wfe, t);
    conv_frag(W1, 64, wf1, t);
    conv_frag(W2, 32, wf2, t);
}

// ---------------------------------------------------------------------------
// node: vskb = bf16(feat@Wv + bv), vrkb = bf16(feat@Wr + br). 128 nodes/block.
// N-dim split into 2 sequential halves (unroll 1) so peak live set is
// a(16)+bfr(8)+acc(16) < 64 VGPR -> genuinely fits the 8-waves/SIMD budget.
// ---------------------------------------------------------------------------
__global__ __launch_bounds__(256, 8) void node_kernel(
    const float* __restrict__ feat,
    const float* __restrict__ bv, const float* __restrict__ br,
    const __bf16* __restrict__ wfv, const __bf16* __restrict__ wfr,
    __bf16* __restrict__ vskb, __bf16* __restrict__ vrkb)
{
    __shared__ __align__(16) __bf16 sT[128 * 64];
    const int tid = threadIdx.x;
    const int lane = tid & 63, w = tid >> 6;
    const int q = lane >> 4, lc = lane & 15;
    const long n0 = (long)blockIdx.x * 128;
    const int wb = w * 32;

    stage_rows_bf16(feat, n0, wb, lane, sT, (long)N_NODES);

    bf16x8 a[2][2];
#pragma unroll
    for (int mt = 0; mt < 2; ++mt)
#pragma unroll
        for (int ks = 0; ks < 2; ++ks)
            a[mt][ks] = afrag(sT, wb + mt * 16 + lc, ks, q);

#pragma unroll 1
    for (int m = 0; m < 2; ++m) {
        const __bf16* wf = (m == 0) ? wfv : wfr;
        const float* bias = (m == 0) ? bv : br;
        __bf16* dstp = (m == 0) ? vskb : vrkb;

#pragma unroll 1
        for (int ntp = 0; ntp < 2; ++ntp) {
            bf16x8 bfr[2][2];
#pragma unroll
            for (int ntl = 0; ntl < 2; ++ntl)
#pragma unroll
                for (int ks = 0; ks < 2; ++ks)
                    bfr[ntl][ks] = *(const bf16x8*)
                        &wf[((size_t)(ks * 4 + ntp * 2 + ntl) * 64 + lane) * 8];

            f32x4 acc[2][2];
#pragma unroll
            for (int mt = 0; mt < 2; ++mt)
#pragma unroll
                for (int ntl = 0; ntl < 2; ++ntl) {
                    f32x4 z = {0.f, 0.f, 0.f, 0.f};
                    acc[mt][ntl] = z;
                }
#pragma unroll
            for (int ks = 0; ks < 2; ++ks)
#pragma unroll
                for (int mt = 0; mt < 2; ++mt)
#pragma unroll
                    for (int ntl = 0; ntl < 2; ++ntl)
                        acc[mt][ntl] = MFMA16(a[mt][ks], bfr[ntl][ks], acc[mt][ntl]);

            float bb[2];
#pragma unroll
            for (int ntl = 0; ntl < 2; ++ntl)
                bb[ntl] = bias[(ntp * 2 + ntl) * 16 + lc];

#pragma unroll
            for (int mt = 0; mt < 2; ++mt)
#pragma unroll
                for (int r = 0; r < 4; ++r) {
                    const long node = n0 + wb + mt * 16 + q * 4 + r;
                    if (node < N_NODES) {
#pragma unroll
                        for (int ntl = 0; ntl < 2; ++ntl)
                            dstp[(size_t)node * 64 + (ntp * 2 + ntl) * 16 + lc] =
                                (__bf16)(acc[mt][ntl][r] + bb[ntl]);
                    }
                }
        }
    }
}

// ---------------------------------------------------------------------------
// edge: h = relu(ek + vsk[src] + vrk[dst] + bek); h1 = relu(h@W1+b1);
//       out = relu(h1@W2+b2). 128 edges/block, barrier-free (wave-private rows).
// Single 16KB LDS buffer, reused 4 ways: efeat(bf16) -> gsum(f16) -> h(bf16)
//   -> h1(bf16).
// Gathers: lane l pulls 16B chunk (l&7) of edge (l>>3)'s vsk AND vrk rows,
//   pre-sums them in f32, stores as f16 into the efeat buffer right after
//   A-frags are pulled.
// GEMM1/GEMM2 N-dim split into 2 sequential halves (unroll 1): peak live set
//   a(16)+bfr(8)+acc(16) ~ 48 VGPR -> fits 64-reg budget WITHOUT spill
//   (R2's launch_bounds(256,8) spilled: WRITE_SIZE 156->641MB scratch traffic).
// 16KB LDS + <=64 VGPR -> 8 blocks/CU -> ~100% occupancy cap.
// ---------------------------------------------------------------------------
__global__ __launch_bounds__(256, 8) void edge_kernel(
    const float* __restrict__ efeat,
    const int* __restrict__ src, const int* __restrict__ dst,
    const __bf16* __restrict__ vskb, const __bf16* __restrict__ vrkb,
    const __bf16* __restrict__ wfe, const __bf16* __restrict__ wf1,
    const __bf16* __restrict__ wf2,
    const float* __restrict__ bek, const float* __restrict__ b1,
    const float* __restrict__ b2,
    float* __restrict__ out)
{
    __shared__ __align__(16) __bf16 sT[128 * 64];
    const int tid = threadIdx.x;
    const int lane = tid & 63, w = tid >> 6;
    const int q = lane >> 4, lc = lane & 15;
    const long e0 = (long)blockIdx.x * 128;
    const int wb = w * 32;
    const int jlo = lane >> 3;   // edge-within-group-of-8
    const int ch  = lane & 7;    // 16B (8-elem) chunk within the 64-col row

    // ---- wave-cooperative gathers, issued FIRST so L2/L3 latency hides
    //      under efeat staging + A-frag pulls; pre-summed to f16 in regs ----
    f16x8 gsum[4];
#pragma unroll
    for (int i = 0; i < 4; ++i) {
        const int r_loc = wb + i * 8 + jlo;
        const long e = e0 + r_loc;
        int si = 0, di = 0;
        if (e < (long)N_EDGES) { si = src[e]; di = dst[e]; }
        bf16x8 gs = *(const bf16x8*)&vskb[(size_t)si * 64 + ch * 8];
        bf16x8 gd = *(const bf16x8*)&vrkb[(size_t)di * 64 + ch * 8];
        f16x8 s;
#pragma unroll
        for (int j = 0; j < 8; ++j)
            s[j] = (_Float16)((float)gs[j] + (float)gd[j]);
        gsum[i] = s;
    }

    // ---- stage efeat (own 32 rows) + pull A-frags ----
    stage_rows_bf16(efeat, e0, wb, lane, sT, (long)N_EDGES);

    bf16x8 a[2][2];
#pragma unroll
    for (int mt = 0; mt < 2; ++mt)
#pragma unroll
        for (int ks = 0; ks < 2; ++ks)
            a[mt][ks] = afrag(sT, wb + mt * 16 + lc, ks, q);

    // ---- efeat now dead for this wave's rows: park f16 gsum in sT (bit-cast,
    //      same 2B slots, same swizzle) ----
#pragma unroll
    for (int i = 0; i < 4; ++i)
        *(bf16x8*)&sT[swz(wb + i * 8 + jlo, ch * 8)] =
            __builtin_bit_cast(bf16x8, gsum[i]);

    // ---- GEMM1: ek = efeat @ Wek, N-split; epilogue reads f16 gsum,
    //      h = relu(acc + gsum + b), writes h (bf16) in place ----
#pragma unroll 1
    for (int ntp = 0; ntp < 2; ++ntp) {
        bf16x8 bfr[2][2];
#pragma unroll
        for (int ntl = 0; ntl < 2; ++ntl)
#pragma unroll
            for (int ks = 0; ks < 2; ++ks)
                bfr[ntl][ks] = *(const bf16x8*)
                    &wfe[((size_t)(ks * 4 + ntp * 2 + ntl) * 64 + lane) * 8];

        f32x4 acc[2][2];
#pragma unroll
        for (int mt = 0; mt < 2; ++mt)
#pragma unroll
            for (int ntl = 0; ntl < 2; ++ntl) {
                f32x4 z = {0.f, 0.f, 0.f, 0.f};
                acc[mt][ntl] = z;
            }
#pragma unroll
        for (int ks = 0; ks < 2; ++ks)
#pragma unroll
            for (int mt = 0; mt < 2; ++mt)
#pragma unroll
                for (int ntl = 0; ntl < 2; ++ntl)
                    acc[mt][ntl] = MFMA16(a[mt][ks], bfr[ntl][ks], acc[mt][ntl]);

        float bb[2];
#pragma unroll
        for (int ntl = 0; ntl < 2; ++ntl)
            bb[ntl] = bek[(ntp * 2 + ntl) * 16 + lc];

#pragma unroll
        for (int mt = 0; mt < 2; ++mt)
#pragma unroll
            for (int r = 0; r < 4; ++r) {
                const int e_loc = wb + mt * 16 + q * 4 + r;
#pragma unroll
                for (int ntl = 0; ntl < 2; ++ntl) {
                    const int col = (ntp * 2 + ntl) * 16 + lc;
                    const int idx = swz(e_loc, col);
                    const float g = (float)u2h(bf2u(sT[idx]));
                    const float hv = fmaxf(acc[mt][ntl][r] + g + bb[ntl], 0.f);
                    sT[idx] = (__bf16)hv;
                }
            }
    }

    // ---- GEMM2: h1 = relu(h @ W1 + b1), N-split ----
    {
        bf16x8 a2[2][2];
#pragma unroll
        for (int mt = 0; mt < 2; ++mt)
#pragma unroll
            for (int ks = 0; ks < 2; ++ks)
                a2[mt][ks] = afrag(sT, wb + mt * 16 + lc, ks, q);

#pragma unroll 1
        for (int ntp = 0; ntp < 2; ++ntp) {
            bf16x8 bfr[2][2];
#pragma unroll
            for (int ntl = 0; ntl < 2; ++ntl)
#pragma unroll
                for (int ks = 0; ks < 2; ++ks)
                    bfr[ntl][ks] = *(const bf16x8*)
                        &wf1[((size_t)(ks * 4 + ntp * 2 + ntl) * 64 + lane) * 8];

            f32x4 acc[2][2];
#pragma unroll
            for (int mt = 0; mt < 2; ++mt)
#pragma unroll
                for (int ntl = 0; ntl < 2; ++ntl) {
                    f32x4 z = {0.f, 0.f, 0.f, 0.f};
                    acc[mt][ntl] = z;
                }
#pragma unroll
            for (int ks = 0; ks < 2; ++ks)
#pragma unroll
                for (int mt = 0; mt < 2; ++mt)
#pragma unroll
                    for (int ntl = 0; ntl < 2; ++ntl)
                        acc[mt][ntl] = MFMA16(a2[mt][ks], bfr[ntl][ks], acc[mt][ntl]);

            float bb[2];
#pragma unroll
            for (int ntl = 0; ntl < 2; ++ntl)
                bb[ntl] = b1[(ntp * 2 + ntl) * 16 + lc];

            // h1 writes: cols of this half only; a2 already fully read.
#pragma unroll
            for (int mt = 0; mt < 2; ++mt)
#pragma unroll
                for (int r = 0; r < 4; ++r) {
                    const int e_loc = wb + mt * 16 + q * 4 + r;
#pragma unroll
                    for (int ntl = 0; ntl < 2; ++ntl) {
                        const int col = (ntp * 2 + ntl) * 16 + lc;
                        const float hv = fmaxf(acc[mt][ntl][r] + bb[ntl], 0.f);
                        sT[swz(e_loc, col)] = (__bf16)hv;
                    }
                }
        }
    }

    // ---- GEMM3: out = relu(h1 @ W2 + b2) (NT=2 -> single half) ----
    {
        bf16x8 a3[2][2];
#pragma unroll
        for (int mt = 0; mt < 2; ++mt)
#pragma unroll
            for (int ks = 0; ks < 2; ++ks)
                a3[mt][ks] = afrag(sT, wb + mt * 16 + lc, ks, q);

        bf16x8 bfr[2][2];
#pragma unroll
        for (int nt = 0; nt < 2; ++nt)
#pragma unroll
            for (int ks = 0; ks < 2; ++ks)
                bfr[nt][ks] = *(const bf16x8*)&wf2[((size_t)(ks * 2 + nt) * 64 + lane) * 8];

        f32x4 acc[2][2];
#pragma unroll
        for (int mt = 0; mt < 2; ++mt)
#pragma unroll
            for (int nt = 0; nt < 2; ++nt) {
                f32x4 z = {0.f, 0.f, 0.f, 0.f};
                acc[mt][nt] = z;
            }
#pragma unroll
        for (int ks = 0; ks < 2; ++ks)
#pragma unroll
            for (int mt = 0; mt < 2; ++mt)
#pragma unroll
                for (int nt = 0; nt < 2; ++nt)
                    acc[mt][nt] = MFMA16(a3[mt][ks], bfr[nt][ks], acc[mt][nt]);

        float bb[2] = {b2[lc], b2[16 + lc]};

#pragma unroll
        for (int mt = 0; mt < 2; ++mt)
#pragma unroll
            for (int r = 0; r < 4; ++r) {
                const long e = e0 + wb + mt * 16 + q * 4 + r;
                if (e < N_EDGES) {
#pragma unroll
                    for (int nt = 0; nt < 2; ++nt)
                        out[(size_t)e * 32 + nt * 16 + lc] =
                            fmaxf(acc[mt][nt][r] + bb[nt], 0.f);
                }
            }
    }
}

extern "C" void kernel_launch(void* const* d_in, const int* in_sizes, int n_in,
                              void* d_out, int out_size, void* d_ws, size_t ws_size,
                              hipStream_t stream) {
    const float* feat  = (const float*)d_in[0];
    const float* efeat = (const float*)d_in[1];
    const int*   src   = (const int*)d_in[2];
    const int*   dst   = (const int*)d_in[3];
    const float* W_vsk = (const float*)d_in[4];
    const float* b_vsk = (const float*)d_in[5];
    const float* W_vrk = (const float*)d_in[6];
    const float* b_vrk = (const float*)d_in[7];
    const float* W_ek  = (const float*)d_in[8];
    const float* b_ek  = (const float*)d_in[9];
    const float* W1    = (const float*)d_in[10];
    const float* b1    = (const float*)d_in[11];
    const float* W2    = (const float*)d_in[12];
    const float* b2    = (const float*)d_in[13];
    float* out = (float*)d_out;

    // ws: vskb(12.8MB) | vrkb(12.8MB) | 5 weight frag blocks (36KB)
    __bf16* vskb = (__bf16*)d_ws;
    __bf16* vrkb = vskb + (size_t)N_NODES * 64;
    __bf16* wfv  = vrkb + (size_t)N_NODES * 64;
    __bf16* wfr  = wfv + 4096;
    __bf16* wfe  = wfr + 4096;
    __bf16* wf1  = wfe + 4096;
    __bf16* wf2  = wf1 + 4096;   // 2048 elems

    prep_kernel<<<1, 256, 0, stream>>>(W_vsk, W_vrk, W_ek, W1, W2,
                                       wfv, wfr, wfe, wf1, wf2);

    const int node_blocks = (N_NODES + 127) / 128;   // 782
    node_kernel<<<node_blocks, 256, 0, stream>>>(feat, b_vsk, b_vrk,
                                                 wfv, wfr, vskb, vrkb);

    const int edge_blocks = (N_EDGES + 127) / 128;   // 9766
    edge_kernel<<<edge_blocks, 256, 0, stream>>>(efeat, src, dst, vskb, vrkb,
                                                 wfe, wf1, wf2,
                                                 b_ek, b1, b2, out);
}

// Round 4
// 608.303 us; speedup vs baseline: 1.1747x; 1.0379x over previous
//
#include <hip/hip_runtime.h>

#define N_NODES 100000
#define N_EDGES 1250000

typedef __bf16 bf16x8 __attribute__((ext_vector_type(8)));
typedef __bf16 bf16x4 __attribute__((ext_vector_type(4)));
typedef _Float16 f16x8 __attribute__((ext_vector_type(8)));
typedef float  f32x4  __attribute__((ext_vector_type(4)));

#define MFMA16(a, b, c) __builtin_amdgcn_mfma_f32_16x16x32_bf16((a), (b), (c), 0, 0, 0)

// bit-pun helpers (all LDS goes through one __bf16-typed buffer; f16 values
// are stored/loaded as raw 16-bit patterns to avoid aliasing hazards)
__device__ __forceinline__ unsigned short bf2u(__bf16 x) {
    union { __bf16 b; unsigned short u; } c; c.b = x; return c.u;
}
__device__ __forceinline__ _Float16 u2h(unsigned short x) {
    union { _Float16 h; unsigned short u; } c; c.u = x; return c.h;
}

// LDS address swizzle: 16B chunks xor'd by row&7 so A-frag b128 reads and
// row-major staging writes both hit the structural LDS minimum (no conflicts).
__device__ __forceinline__ int swz(int row, int k) {
    return row * 64 + (((k >> 3) ^ (row & 7)) << 3) + (k & 7);
}

// Stage 32 rows (this wave's slice) of a row-major [nrows x 64] fp32 matrix
// into LDS as bf16, swizzled. Coalesced float4 loads; barrier-free (each wave
// touches only rows [wb, wb+32)).
__device__ __forceinline__ void stage_rows_bf16(
    const float* __restrict__ srcmat, long row0, int wb, int lane,
    __bf16* sT, long nrows)
{
#pragma unroll
    for (int i = 0; i < 8; ++i) {
        const int f = (i * 64 + lane) * 4;   // flat over 32*64 floats
        const int rl = f >> 6;
        const int k  = f & 63;
        const int r_loc = wb + rl;
        const long r = row0 + r_loc;
        float4 v = {0.f, 0.f, 0.f, 0.f};
        if (r < nrows) v = *(const float4*)&srcmat[(size_t)r * 64 + k];
        bf16x4 pk = { (__bf16)v.x, (__bf16)v.y, (__bf16)v.z, (__bf16)v.w };
        *(bf16x4*)&sT[swz(r_loc, k)] = pk;
    }
}

// A-frag for mfma_f32_16x16x32_bf16: lane holds A[m=lane&15][k=quad*8+j]
__device__ __forceinline__ bf16x8 afrag(const __bf16* sT, int row, int ks, int q) {
    return *(const bf16x8*)&sT[swz(row, ks * 32 + q * 8)];
}

// ---------------------------------------------------------------------------
// prep: convert the 5 weight matrices to bf16 in B-frag order in ws.
// Frag slot s = (ks*NT + nt)*64 + lane holds B[k=ks*32+(lane>>4)*8+j][n=nt*16+(lane&15)]
// ---------------------------------------------------------------------------
__device__ __forceinline__ void conv_frag(const float* __restrict__ W, int N,
                                          __bf16* __restrict__ dst, int tid) {
    const int NT = N / 16;
    const int slots = 2 * NT * 64;
    for (int s = tid; s < slots; s += 256) {
        const int ks = s / (NT * 64);
        const int nt = (s / 64) % NT;
        const int lane = s % 64;
        const int q = lane >> 4, lc = lane & 15;
#pragma unroll
        for (int j = 0; j < 8; ++j) {
            const int k = ks * 32 + q * 8 + j;
            dst[(size_t)s * 8 + j] = (__bf16)W[(size_t)k * N + nt * 16 + lc];
        }
    }
}

__global__ __launch_bounds__(256) void prep_kernel(
    const float* __restrict__ Wv, const float* __restrict__ Wr,
    const float* __restrict__ We, const float* __restrict__ W1,
    const float* __restrict__ W2,
    __bf16* wfv, __bf16* wfr, __bf16* wfe, __bf16* wf1, __bf16* wf2)
{
    const int t = threadIdx.x;
    conv_frag(Wv, 64, wfv, t);
    conv_frag(Wr, 64, wfr, t);
    conv_frag(We, 64, wfe, t);
    conv_frag(W1, 64, wf1, t);
    conv_frag(W2, 32, wf2, t);
}

// ---------------------------------------------------------------------------
// node: vskb = bf16(feat@Wv + bv), vrkb = bf16(feat@Wr + br). 128 nodes/block.
// N-dim split into 2 sequential halves (unroll 1) so peak live set is
// a(16)+bfr(8)+acc(16) < 64 VGPR -> genuinely fits the 8-waves/SIMD budget.
// ---------------------------------------------------------------------------
__global__ __launch_bounds__(256, 8) void node_kernel(
    const float* __restrict__ feat,
    const float* __restrict__ bv, const float* __restrict__ br,
    const __bf16* __restrict__ wfv, const __bf16* __restrict__ wfr,
    __bf16* __restrict__ vskb, __bf16* __restrict__ vrkb)
{
    __shared__ __align__(16) __bf16 sT[128 * 64];
    const int tid = threadIdx.x;
    const int lane = tid & 63, w = tid >> 6;
    const int q = lane >> 4, lc = lane & 15;
    const long n0 = (long)blockIdx.x * 128;
    const int wb = w * 32;

    stage_rows_bf16(feat, n0, wb, lane, sT, (long)N_NODES);

    bf16x8 a[2][2];
#pragma unroll
    for (int mt = 0; mt < 2; ++mt)
#pragma unroll
        for (int ks = 0; ks < 2; ++ks)
            a[mt][ks] = afrag(sT, wb + mt * 16 + lc, ks, q);

#pragma unroll 1
    for (int m = 0; m < 2; ++m) {
        const __bf16* wf = (m == 0) ? wfv : wfr;
        const float* bias = (m == 0) ? bv : br;
        __bf16* dstp = (m == 0) ? vskb : vrkb;

#pragma unroll 1
        for (int ntp = 0; ntp < 2; ++ntp) {
            bf16x8 bfr[2][2];
#pragma unroll
            for (int ntl = 0; ntl < 2; ++ntl)
#pragma unroll
                for (int ks = 0; ks < 2; ++ks)
                    bfr[ntl][ks] = *(const bf16x8*)
                        &wf[((size_t)(ks * 4 + ntp * 2 + ntl) * 64 + lane) * 8];

            f32x4 acc[2][2];
#pragma unroll
            for (int mt = 0; mt < 2; ++mt)
#pragma unroll
                for (int ntl = 0; ntl < 2; ++ntl) {
                    f32x4 z = {0.f, 0.f, 0.f, 0.f};
                    acc[mt][ntl] = z;
                }
#pragma unroll
            for (int ks = 0; ks < 2; ++ks)
#pragma unroll
                for (int mt = 0; mt < 2; ++mt)
#pragma unroll
                    for (int ntl = 0; ntl < 2; ++ntl)
                        acc[mt][ntl] = MFMA16(a[mt][ks], bfr[ntl][ks], acc[mt][ntl]);

            float bb[2];
#pragma unroll
            for (int ntl = 0; ntl < 2; ++ntl)
                bb[ntl] = bias[(ntp * 2 + ntl) * 16 + lc];

#pragma unroll
            for (int mt = 0; mt < 2; ++mt)
#pragma unroll
                for (int r = 0; r < 4; ++r) {
                    const long node = n0 + wb + mt * 16 + q * 4 + r;
                    if (node < N_NODES) {
#pragma unroll
                        for (int ntl = 0; ntl < 2; ++ntl)
                            dstp[(size_t)node * 64 + (ntp * 2 + ntl) * 16 + lc] =
                                (__bf16)(acc[mt][ntl][r] + bb[ntl]);
                    }
                }
        }
    }
}

// ---------------------------------------------------------------------------
// edge: h = relu(ek + vsk[src] + vrk[dst] + bek); h1 = relu(h@W1+b1);
//       out = relu(h1@W2+b2). 128 edges/block, barrier-free (wave-private rows).
// Single 16KB LDS buffer, reused 4 ways: efeat(bf16) -> gsum(f16) -> h(bf16)
//   -> h1(bf16).
// Register discipline (R3 post-mortem): ONLY the src/dst indices (8 VGPR) are
//   held across staging. The vskb/vrkb gathers issue AFTER the A-frag pull and
//   write their f16 pre-sum straight into sT -- no 16-reg gsum hold, no spill.
//   Gather latency is covered by TLP (8 waves/SIMD) + GEMM1's independent
//   B-frag loads and MFMAs.
// GEMM1/GEMM2 N-dim split into 2 sequential halves (unroll 1): peak live set
//   a(16)+bfr(8)+acc(16) ~ 48 VGPR -> fits the 64-reg budget for real.
// 16KB LDS + <=64 VGPR -> 8 blocks/CU -> ~100% occupancy cap.
// ---------------------------------------------------------------------------
__global__ __launch_bounds__(256, 8) void edge_kernel(
    const float* __restrict__ efeat,
    const int* __restrict__ src, const int* __restrict__ dst,
    const __bf16* __restrict__ vskb, const __bf16* __restrict__ vrkb,
    const __bf16* __restrict__ wfe, const __bf16* __restrict__ wf1,
    const __bf16* __restrict__ wf2,
    const float* __restrict__ bek, const float* __restrict__ b1,
    const float* __restrict__ b2,
    float* __restrict__ out)
{
    __shared__ __align__(16) __bf16 sT[128 * 64];
    const int tid = threadIdx.x;
    const int lane = tid & 63, w = tid >> 6;
    const int q = lane >> 4, lc = lane & 15;
    const long e0 = (long)blockIdx.x * 128;
    const int wb = w * 32;
    const int jlo = lane >> 3;   // edge-within-group-of-8
    const int ch  = lane & 7;    // 16B (8-elem) chunk within the 64-col row

    // ---- index prefetch only (8 VGPRs live across staging) ----
    int si[4], di[4];
#pragma unroll
    for (int i = 0; i < 4; ++i) {
        const long e = e0 + wb + i * 8 + jlo;
        si[i] = 0; di[i] = 0;
        if (e < (long)N_EDGES) { si[i] = src[e]; di[i] = dst[e]; }
    }

    // ---- stage efeat (own 32 rows) + pull A-frags ----
    stage_rows_bf16(efeat, e0, wb, lane, sT, (long)N_EDGES);

    bf16x8 a[2][2];
#pragma unroll
    for (int mt = 0; mt < 2; ++mt)
#pragma unroll
        for (int ks = 0; ks < 2; ++ks)
            a[mt][ks] = afrag(sT, wb + mt * 16 + lc, ks, q);

    // ---- gathers: lane l pulls 16B chunk (l&7) of edge (l>>3)'s vsk AND vrk
    //      rows, pre-sums in f32, parks as f16 in sT (efeat now dead).
    //      No long-lived registers; latency hidden by TLP + GEMM1 issue. ----
#pragma unroll
    for (int i = 0; i < 4; ++i) {
        bf16x8 gs = *(const bf16x8*)&vskb[(size_t)si[i] * 64 + ch * 8];
        bf16x8 gd = *(const bf16x8*)&vrkb[(size_t)di[i] * 64 + ch * 8];
        f16x8 s;
#pragma unroll
        for (int j = 0; j < 8; ++j)
            s[j] = (_Float16)((float)gs[j] + (float)gd[j]);
        *(bf16x8*)&sT[swz(wb + i * 8 + jlo, ch * 8)] =
            __builtin_bit_cast(bf16x8, s);
    }

    // ---- GEMM1: ek = efeat @ Wek, N-split; epilogue reads f16 gsum,
    //      h = relu(acc + gsum + b), writes h (bf16) in place ----
#pragma unroll 1
    for (int ntp = 0; ntp < 2; ++ntp) {
        bf16x8 bfr[2][2];
#pragma unroll
        for (int ntl = 0; ntl < 2; ++ntl)
#pragma unroll
            for (int ks = 0; ks < 2; ++ks)
                bfr[ntl][ks] = *(const bf16x8*)
                    &wfe[((size_t)(ks * 4 + ntp * 2 + ntl) * 64 + lane) * 8];

        f32x4 acc[2][2];
#pragma unroll
        for (int mt = 0; mt < 2; ++mt)
#pragma unroll
            for (int ntl = 0; ntl < 2; ++ntl) {
                f32x4 z = {0.f, 0.f, 0.f, 0.f};
                acc[mt][ntl] = z;
            }
#pragma unroll
        for (int ks = 0; ks < 2; ++ks)
#pragma unroll
            for (int mt = 0; mt < 2; ++mt)
#pragma unroll
                for (int ntl = 0; ntl < 2; ++ntl)
                    acc[mt][ntl] = MFMA16(a[mt][ks], bfr[ntl][ks], acc[mt][ntl]);

        float bb[2];
#pragma unroll
        for (int ntl = 0; ntl < 2; ++ntl)
            bb[ntl] = bek[(ntp * 2 + ntl) * 16 + lc];

#pragma unroll
        for (int mt = 0; mt < 2; ++mt)
#pragma unroll
            for (int r = 0; r < 4; ++r) {
                const int e_loc = wb + mt * 16 + q * 4 + r;
#pragma unroll
                for (int ntl = 0; ntl < 2; ++ntl) {
                    const int col = (ntp * 2 + ntl) * 16 + lc;
                    const int idx = swz(e_loc, col);
                    const float g = (float)u2h(bf2u(sT[idx]));
                    const float hv = fmaxf(acc[mt][ntl][r] + g + bb[ntl], 0.f);
                    sT[idx] = (__bf16)hv;
                }
            }
    }

    // ---- GEMM2: h1 = relu(h @ W1 + b1), N-split ----
    {
        bf16x8 a2[2][2];
#pragma unroll
        for (int mt = 0; mt < 2; ++mt)
#pragma unroll
            for (int ks = 0; ks < 2; ++ks)
                a2[mt][ks] = afrag(sT, wb + mt * 16 + lc, ks, q);

#pragma unroll 1
        for (int ntp = 0; ntp < 2; ++ntp) {
            bf16x8 bfr[2][2];
#pragma unroll
            for (int ntl = 0; ntl < 2; ++ntl)
#pragma unroll
                for (int ks = 0; ks < 2; ++ks)
                    bfr[ntl][ks] = *(const bf16x8*)
                        &wf1[((size_t)(ks * 4 + ntp * 2 + ntl) * 64 + lane) * 8];

            f32x4 acc[2][2];
#pragma unroll
            for (int mt = 0; mt < 2; ++mt)
#pragma unroll
                for (int ntl = 0; ntl < 2; ++ntl) {
                    f32x4 z = {0.f, 0.f, 0.f, 0.f};
                    acc[mt][ntl] = z;
                }
#pragma unroll
            for (int ks = 0; ks < 2; ++ks)
#pragma unroll
                for (int mt = 0; mt < 2; ++mt)
#pragma unroll
                    for (int ntl = 0; ntl < 2; ++ntl)
                        acc[mt][ntl] = MFMA16(a2[mt][ks], bfr[ntl][ks], acc[mt][ntl]);

            float bb[2];
#pragma unroll
            for (int ntl = 0; ntl < 2; ++ntl)
                bb[ntl] = b1[(ntp * 2 + ntl) * 16 + lc];

            // h1 writes: cols of this half only; a2 already fully read.
#pragma unroll
            for (int mt = 0; mt < 2; ++mt)
#pragma unroll
                for (int r = 0; r < 4; ++r) {
                    const int e_loc = wb + mt * 16 + q * 4 + r;
#pragma unroll
                    for (int ntl = 0; ntl < 2; ++ntl) {
                        const int col = (ntp * 2 + ntl) * 16 + lc;
                        const float hv = fmaxf(acc[mt][ntl][r] + bb[ntl], 0.f);
                        sT[swz(e_loc, col)] = (__bf16)hv;
                    }
                }
        }
    }

    // ---- GEMM3: out = relu(h1 @ W2 + b2) (NT=2 -> single half) ----
    {
        bf16x8 a3[2][2];
#pragma unroll
        for (int mt = 0; mt < 2; ++mt)
#pragma unroll
            for (int ks = 0; ks < 2; ++ks)
                a3[mt][ks] = afrag(sT, wb + mt * 16 + lc, ks, q);

        bf16x8 bfr[2][2];
#pragma unroll
        for (int nt = 0; nt < 2; ++nt)
#pragma unroll
            for (int ks = 0; ks < 2; ++ks)
                bfr[nt][ks] = *(const bf16x8*)&wf2[((size_t)(ks * 2 + nt) * 64 + lane) * 8];

        f32x4 acc[2][2];
#pragma unroll
        for (int mt = 0; mt < 2; ++mt)
#pragma unroll
            for (int nt = 0; nt < 2; ++nt) {
                f32x4 z = {0.f, 0.f, 0.f, 0.f};
                acc[mt][nt] = z;
            }
#pragma unroll
        for (int ks = 0; ks < 2; ++ks)
#pragma unroll
            for (int mt = 0; mt < 2; ++mt)
#pragma unroll
                for (int nt = 0; nt < 2; ++nt)
                    acc[mt][nt] = MFMA16(a3[mt][ks], bfr[nt][ks], acc[mt][nt]);

        float bb[2] = {b2[lc], b2[16 + lc]};

#pragma unroll
        for (int mt = 0; mt < 2; ++mt)
#pragma unroll
            for (int r = 0; r < 4; ++r) {
                const long e = e0 + wb + mt * 16 + q * 4 + r;
                if (e < N_EDGES) {
#pragma unroll
                    for (int nt = 0; nt < 2; ++nt)
                        out[(size_t)e * 32 + nt * 16 + lc] =
                            fmaxf(acc[mt][nt][r] + bb[nt], 0.f);
                }
            }
    }
}

extern "C" void kernel_launch(void* const* d_in, const int* in_sizes, int n_in,
                              void* d_out, int out_size, void* d_ws, size_t ws_size,
                              hipStream_t stream) {
    const float* feat  = (const float*)d_in[0];
    const float* efeat = (const float*)d_in[1];
    const int*   src   = (const int*)d_in[2];
    const int*   dst   = (const int*)d_in[3];
    const float* W_vsk = (const float*)d_in[4];
    const float* b_vsk = (const float*)d_in[5];
    const float* W_vrk = (const float*)d_in[6];
    const float* b_vrk = (const float*)d_in[7];
    const float* W_ek  = (const float*)d_in[8];
    const float* b_ek  = (const float*)d_in[9];
    const float* W1    = (const float*)d_in[10];
    const float* b1    = (const float*)d_in[11];
    const float* W2    = (const float*)d_in[12];
    const float* b2    = (const float*)d_in[13];
    float* out = (float*)d_out;

    // ws: vskb(12.8MB) | vrkb(12.8MB) | 5 weight frag blocks (36KB)
    __bf16* vskb = (__bf16*)d_ws;
    __bf16* vrkb = vskb + (size_t)N_NODES * 64;
    __bf16* wfv  = vrkb + (size_t)N_NODES * 64;
    __bf16* wfr  = wfv + 4096;
    __bf16* wfe  = wfr + 4096;
    __bf16* wf1  = wfe + 4096;
    __bf16* wf2  = wf1 + 4096;   // 2048 elems

    prep_kernel<<<1, 256, 0, stream>>>(W_vsk, W_vrk, W_ek, W1, W2,
                                       wfv, wfr, wfe, wf1, wf2);

    const int node_blocks = (N_NODES + 127) / 128;   // 782
    node_kernel<<<node_blocks, 256, 0, stream>>>(feat, b_vsk, b_vrk,
                                                 wfv, wfr, vskb, vrkb);

    const int edge_blocks = (N_EDGES + 127) / 128;   // 9766
    edge_kernel<<<edge_blocks, 256, 0, stream>>>(efeat, src, dst, vskb, vrkb,
                                                 wfe, wf1, wf2,
                                                 b_ek, b1, b2, out);
}